// Round 1
// baseline (18.336 us; speedup 1.0000x reference)
//
#include <hip/hip_runtime.h>

// Problem constants (match reference setup_inputs)
#define BB 16
#define SS 256
#define NLL 66
#define VMAXX 8
#define CC 6          // CORE_IDX = [1..6]
#define CLAMP_MIN 1e-6f

// d_ws layout: [0] double accumulator

__global__ void urloss_init(double* __restrict__ acc) {
    if (threadIdx.x == 0) acc[0] = 0.0;
}

// One block (1 wave, 64 lanes) per (b, v, c) cell.
// Pass 1: min1/min2/argmin of log_neg over valid tokens t < orig_l.
// Pass 2: sum relu(log_core[j] - (j==argmin ? min2 : min1)) over valid j.
__global__ __launch_bounds__(64)
void urloss_main(const float* __restrict__ log_pa,
                 const int* __restrict__ v_label,
                 const int* __restrict__ v_l,
                 const int* __restrict__ orig_l,
                 double* __restrict__ acc) {
    const int blk = blockIdx.x;                 // b*VMAX*C + v*C + c
    const int c = blk % CC;
    const int v = (blk / CC) % VMAXX;
    const int b = blk / (CC * VMAXX);

    if (v >= v_l[b]) return;                    // v_valid weight == 0
    const int p    = v_label[b * VMAXX + v];    // gathered predicate row
    const int orig = orig_l[b];
    const int lane = threadIdx.x;

    // element [b][p][t][1+c]
    const float* row = log_pa + ((size_t)(b * SS + p) * SS) * NLL + (1 + c);

    float vals[4];
    float m1 = 1e30f, m2 = 1e30f;
    int   idx = -1;

#pragma unroll
    for (int k = 0; k < 4; ++k) {
        const int t = lane + 64 * k;            // t < SS always
        const float lc = row[(size_t)t * NLL];  // log_core
        vals[k] = lc;
        if (t < orig) {
            const float ln = logf(fmaxf(1.0f - expf(lc), CLAMP_MIN)); // log_neg
            if (ln < m1) { m2 = m1; m1 = ln; idx = t; }
            else if (ln < m2) { m2 = ln; }
        }
    }

    // wave-reduce (m1, m2, idx) triples; lane 0 ends with global result
#pragma unroll
    for (int off = 32; off >= 1; off >>= 1) {
        const float o1 = __shfl_down(m1, off);
        const float o2 = __shfl_down(m2, off);
        const int   oi = __shfl_down(idx, off);
        if (o1 < m1) { m2 = fminf(m1, o2); m1 = o1; idx = oi; }
        else         { m2 = fminf(m2, o1); }
    }
    m1  = __shfl(m1, 0);
    m2  = __shfl(m2, 0);
    idx = __shfl(idx, 0);

    float sum = 0.0f;
#pragma unroll
    for (int k = 0; k < 4; ++k) {
        const int t = lane + 64 * k;
        if (t < orig) {
            const float sel = (t == idx) ? m2 : m1;
            sum += fmaxf(vals[k] - sel, 0.0f);  // relu(log_core - min_neg)
        }
    }
#pragma unroll
    for (int off = 32; off >= 1; off >>= 1) sum += __shfl_down(sum, off);

    if (lane == 0) atomicAdd(acc, (double)sum);
}

__global__ void urloss_final(const double* __restrict__ acc,
                             const int* __restrict__ v_l,
                             float* __restrict__ out) {
    if (threadIdx.x == 0) {
        int norm = 0;
        for (int b = 0; b < BB; ++b) norm += v_l[b];
        out[0] = (float)(acc[0] / (double)norm);
    }
}

extern "C" void kernel_launch(void* const* d_in, const int* in_sizes, int n_in,
                              void* d_out, int out_size, void* d_ws, size_t ws_size,
                              hipStream_t stream) {
    const float* log_pa  = (const float*)d_in[0];
    const int*   v_label = (const int*)d_in[1];
    const int*   v_l     = (const int*)d_in[2];
    const int*   orig_l  = (const int*)d_in[3];
    double* acc = (double*)d_ws;

    urloss_init<<<1, 64, 0, stream>>>(acc);
    urloss_main<<<BB * VMAXX * CC, 64, 0, stream>>>(log_pa, v_label, v_l, orig_l, acc);
    urloss_final<<<1, 64, 0, stream>>>(acc, v_l, (float*)d_out);
}

// Round 2
// 12.452 us; speedup vs baseline: 1.4725x; 1.4725x over previous
//
#include <hip/hip_runtime.h>

// Problem constants (match reference setup_inputs)
#define BB 16
#define SS 256
#define NLL 66
#define VMAXX 8
#define CC 6          // CORE_IDX = [1..6]
#define CLAMP_MIN 1e-6f
#define NBLK (BB * VMAXX * CC)   // 768

// d_ws layout: [0..NBLK) double partial sums (one per main block)

// One block (1 wave, 64 lanes) per (b, v, c) cell.
// Pass 1: min1/min2/argmin of log_neg over valid tokens t < orig_l.
// Pass 2: sum relu(log_core[j] - (j==argmin ? min2 : min1)) over valid j.
// Writes its partial (double) to ws[blockIdx.x] unconditionally.
__global__ __launch_bounds__(64)
void urloss_main(const float* __restrict__ log_pa,
                 const int* __restrict__ v_label,
                 const int* __restrict__ v_l,
                 const int* __restrict__ orig_l,
                 double* __restrict__ partial) {
    const int blk = blockIdx.x;                 // b*VMAX*C + v*C + c
    const int c = blk % CC;
    const int v = (blk / CC) % VMAXX;
    const int b = blk / (CC * VMAXX);
    const int lane = threadIdx.x;

    if (v >= v_l[b]) {                          // v_valid weight == 0
        if (lane == 0) partial[blk] = 0.0;
        return;
    }
    const int p    = v_label[b * VMAXX + v];    // gathered predicate row
    const int orig = orig_l[b];

    // element [b][p][t][1+c]
    const float* row = log_pa + ((size_t)(b * SS + p) * SS) * NLL + (1 + c);

    float vals[4];
    float m1 = 1e30f, m2 = 1e30f;
    int   idx = -1;

#pragma unroll
    for (int k = 0; k < 4; ++k) {
        const int t = lane + 64 * k;            // t < SS always
        const float lc = row[(size_t)t * NLL];  // log_core
        vals[k] = lc;
        if (t < orig) {
            const float ln = logf(fmaxf(1.0f - expf(lc), CLAMP_MIN)); // log_neg
            if (ln < m1) { m2 = m1; m1 = ln; idx = t; }
            else if (ln < m2) { m2 = ln; }
        }
    }

    // wave-reduce (m1, m2, idx) triples; broadcast result
#pragma unroll
    for (int off = 32; off >= 1; off >>= 1) {
        const float o1 = __shfl_down(m1, off);
        const float o2 = __shfl_down(m2, off);
        const int   oi = __shfl_down(idx, off);
        if (o1 < m1) { m2 = fminf(m1, o2); m1 = o1; idx = oi; }
        else         { m2 = fminf(m2, o1); }
    }
    m1  = __shfl(m1, 0);
    m2  = __shfl(m2, 0);
    idx = __shfl(idx, 0);

    float sum = 0.0f;
#pragma unroll
    for (int k = 0; k < 4; ++k) {
        const int t = lane + 64 * k;
        if (t < orig) {
            const float sel = (t == idx) ? m2 : m1;
            sum += fmaxf(vals[k] - sel, 0.0f);  // relu(log_core - min_neg)
        }
    }
#pragma unroll
    for (int off = 32; off >= 1; off >>= 1) sum += __shfl_down(sum, off);

    if (lane == 0) partial[blk] = (double)sum;
}

// Single wave: reduce NBLK doubles + normalize.
__global__ __launch_bounds__(64)
void urloss_reduce(const double* __restrict__ partial,
                   const int* __restrict__ v_l,
                   float* __restrict__ out) {
    const int lane = threadIdx.x;
    double s = 0.0;
#pragma unroll
    for (int k = 0; k < NBLK / 64; ++k)         // 12 loads/lane
        s += partial[lane + 64 * k];
#pragma unroll
    for (int off = 32; off >= 1; off >>= 1)
        s += __shfl_down(s, off);
    if (lane == 0) {
        int norm = 0;
        for (int b = 0; b < BB; ++b) norm += v_l[b];
        out[0] = (float)(s / (double)norm);
    }
}

extern "C" void kernel_launch(void* const* d_in, const int* in_sizes, int n_in,
                              void* d_out, int out_size, void* d_ws, size_t ws_size,
                              hipStream_t stream) {
    const float* log_pa  = (const float*)d_in[0];
    const int*   v_label = (const int*)d_in[1];
    const int*   v_l     = (const int*)d_in[2];
    const int*   orig_l  = (const int*)d_in[3];
    double* partial = (double*)d_ws;

    urloss_main<<<NBLK, 64, 0, stream>>>(log_pa, v_label, v_l, orig_l, partial);
    urloss_reduce<<<1, 64, 0, stream>>>(partial, v_l, (float*)d_out);
}